// Round 18
// baseline (172.831 us; speedup 1.0000x reference)
//
#include <hip/hip_runtime.h>
#include <hip/hip_bf16.h>

typedef unsigned short u16;
typedef unsigned int u32;
typedef float  f32x4 __attribute__((ext_vector_type(4)));
typedef short  s16x8 __attribute__((ext_vector_type(8)));

#define DEV static __device__ __forceinline__

DEV u16 f2bf(float f){ union{float f; unsigned int i;} c; c.f=f; unsigned int i=c.i;
                       return (u16)((i + 0x7FFFu + ((i>>16)&1u))>>16); }

// packed 2x f32 -> bf16x2 (v_cvt_pk_bf16_f32), low word = a
DEV u32 pkbf(float a, float b){
  union{ __hip_bfloat162 h; u32 u; } c;
  c.h = __float22bfloat162_rn(make_float2(a, b));
  return c.u;
}

DEV float exp2a(float x){
#if __has_builtin(__builtin_amdgcn_exp2f)
  return __builtin_amdgcn_exp2f(x);
#else
  return exp2f(x);
#endif
}

// 16x16x32 A/B fragment, plain bf16 layout: 4 contiguous bf16 at p, 4 at p+16.
// Same k-map mu(lq,e) for all operands (incl. D->B repacks) -> permutation-safe.
DEV s16x8 ld_frag(const u16* p){
  union{ s16x8 v; uint2 u[2]; } r;
  r.u[0] = *(const uint2*)(p);
  r.u[1] = *(const uint2*)(p+16);
  return r.v;
}

// Same fragment built from an fp32 source (inline convert; layout-identical).
DEV s16x8 ld_frag_f32(const float* p){
  float4 a = *(const float4*)(p);
  float4 b = *(const float4*)(p+16);
  union{ s16x8 v; u32 u[4]; } r;
  r.u[0]=pkbf(a.x,a.y); r.u[1]=pkbf(a.z,a.w);
  r.u[2]=pkbf(b.x,b.y); r.u[3]=pkbf(b.z,b.w);
  return r.v;
}

// ---------------- Kernel 1: K/V projection (x AND W read as fp32, converted inline) ----------------
// K stored [bh][n][kk'] (kk' fragment-permuted); V stored transposed
// [bh][dv][n'] (n' fragment-permuted within each 64-tile).
// Piggyback: 64 V-side blocks also convert Wq fp32->bf16 (no extra dispatch).
__global__ __launch_bounds__(256) void kv_kernel(
    const float* __restrict__ x32, const float* __restrict__ Wk32,
    const float* __restrict__ Wv32, const float* __restrict__ Wq32,
    u16* __restrict__ kbuf, u16* __restrict__ vbuf, u16* __restrict__ wq16)
{
  const int isV = blockIdx.z;
  const float* W32 = isV ? Wv32 : Wk32;
  const int m0 = blockIdx.x*64, j0 = blockIdx.y*64;
  __shared__ u16 at[64][40];
  __shared__ u16 bt[64][40];
  const int tid = threadIdx.x, lane = tid&63, w = tid>>6;
  const int wm = w>>1, wn = w&1;
  const int l16 = lane&15, lq = lane>>4;
  f32x4 acc[2][2] = {};
  const int srow = tid>>2, scol = (tid&3)*8;
  for (int c0=0;c0<256;c0+=32){
    {
      const float* xs = x32 + (size_t)(m0+srow)*256 + c0 + scol;
      float4 a = *(const float4*)xs;
      float4 b = *(const float4*)(xs+4);
      uint4 st; st.x=pkbf(a.x,a.y); st.y=pkbf(a.z,a.w); st.z=pkbf(b.x,b.y); st.w=pkbf(b.z,b.w);
      *(uint4*)&at[srow][scol] = st;
    }
    {
      const float* wsrc = W32 + (size_t)(j0+srow)*256 + c0 + scol;
      float4 a = *(const float4*)wsrc;
      float4 b = *(const float4*)(wsrc+4);
      uint4 st; st.x=pkbf(a.x,a.y); st.y=pkbf(a.z,a.w); st.z=pkbf(b.x,b.y); st.w=pkbf(b.z,b.w);
      *(uint4*)&bt[srow][scol] = st;
    }
    __syncthreads();
    s16x8 af[2], bfr[2];
    #pragma unroll
    for(int mf=0;mf<2;mf++) af[mf]  = ld_frag(&at[wm*32+mf*16+l16][lq*4]);
    #pragma unroll
    for(int nf=0;nf<2;nf++) bfr[nf] = ld_frag(&bt[wn*32+nf*16+l16][lq*4]);
    #pragma unroll
    for(int mf=0;mf<2;mf++)
      #pragma unroll
      for(int nf=0;nf<2;nf++)
        acc[mf][nf] = __builtin_amdgcn_mfma_f32_16x16x32_bf16(af[mf], bfr[nf], acc[mf][nf],0,0,0);
    __syncthreads();
  }
  // D layout: col = l16, row = lq*4 + r
  if (!isV){
    #pragma unroll
    for(int mf=0;mf<2;mf++)
      #pragma unroll
      for(int nf=0;nf<2;nf++){
        const int j  = j0 + wn*32 + nf*16 + l16;
        const int hh = j>>6;
        const int kkp = wn*32 + (l16>>2)*8 + nf*4 + (l16&3);   // permuted kk
        #pragma unroll
        for(int r=0;r<4;r++){
          int m = m0 + wm*32 + mf*16 + lq*4 + r;
          int blx = m>>11, n = m&2047;
          kbuf[(size_t)((blx<<3)|hh)*131072 + (size_t)n*64 + kkp] = f2bf(acc[mf][nf][r]);
        }
      }
  } else {
    const int blx = m0>>11;
    #pragma unroll
    for(int mf=0;mf<2;mf++){
      const int nn = (m0&2047) + wm*32 + lq*8 + mf*4;          // permuted n-within-tile
      #pragma unroll
      for(int nf=0;nf<2;nf++){
        const int j  = j0 + wn*32 + nf*16 + l16;
        const int hh = j>>6, kk = j&63;
        uint2 st;
        st.x = pkbf(acc[mf][nf][0], acc[mf][nf][1]);
        st.y = pkbf(acc[mf][nf][2], acc[mf][nf][3]);
        *(uint2*)&vbuf[(size_t)((blx<<3)|hh)*131072 + (size_t)kk*2048 + nn] = st;
      }
    }
    // ---- piggyback: Wq fp32 -> bf16 (64 blocks x 2048 elems) ----
    if (j0==0 && blockIdx.x < 64){
      const int base = blockIdx.x*2048 + tid*8;
      float4 a = *(const float4*)(Wq32 + base);
      float4 b = *(const float4*)(Wq32 + base + 4);
      uint4 st; st.x=pkbf(a.x,a.y); st.y=pkbf(a.z,a.w); st.z=pkbf(b.x,b.y); st.w=pkbf(b.z,b.w);
      *(uint4*)(wq16 + base) = st;
    }
  }
}

// ---------------- Kernel 2: fused Q-projection + flash attention ----------------
// r16 compute structure + DOUBLE-buffered LDS with ONE barrier/tile (no setprio
// — isolating r10's confound). 128 q-rows/block; XCD-swizzled grid; scale folded
// into Q; NO-max softmax (P=exp2(S) raw); l via ones-MFMA; unpadded [2][64][64]
// LDS, both-sides XOR swizzle (0 conflicts); Wq read as bf16 (piggyback-converted).
__global__ __launch_bounds__(256) void attn_kernel(
    const float* __restrict__ x32, const u16* __restrict__ wq16,
    const u16* __restrict__ kb, const u16* __restrict__ vb,
    u16* __restrict__ cat, int bh_per_xcd)
{
  const int lin = blockIdx.x;
  const int xcd = lin & 7, slot = lin >> 3;
  const int bhl = xcd*bh_per_xcd + (slot>>4);     // 16 q-tiles per bh
  const int n0  = (slot & 15) * 128;
  const int bl = bhl>>3, h = bhl&7;
  const float* xg = x32 + (size_t)bl*524288;
  const u16* kg = kb + (size_t)bhl*131072;        // [n][kk'] pre-permuted
  const u16* vg = vb + (size_t)bhl*131072;        // [dv][n'] pre-permuted
  u16* catp = cat + (size_t)bl*1048576 + h*64;
  const int tid=threadIdx.x, lane=tid&63, w=tid>>6;
  const int l16=lane&15, lq=lane>>4;

  __shared__ __align__(16) u16 kt[2][64][64];
  __shared__ __align__(16) u16 vt[2][64][64];

  // ---- Q on the fly for 2 subtiles; scale (0.125*log2e) folded into qf ----
  s16x8 qf[2][2];
  {
    const u16* wqh = wq16 + (size_t)h*16384;
    s16x8 xf[2][8];
    #pragma unroll
    for(int sub=0;sub<2;sub++){
      const int row = n0 + w*32 + sub*16 + l16;
      #pragma unroll
      for(int kc8=0;kc8<8;kc8++)
        xf[sub][kc8] = ld_frag_f32(xg + (size_t)row*256 + kc8*32 + lq*4);
    }
    f32x4 dq[2][4] = {};
    #pragma unroll
    for(int df=0;df<4;df++)
      #pragma unroll
      for(int kc8=0;kc8<8;kc8++){
        s16x8 wf = ld_frag(wqh + (size_t)(df*16+l16)*256 + kc8*32 + lq*4);
        dq[0][df] = __builtin_amdgcn_mfma_f32_16x16x32_bf16(wf, xf[0][kc8], dq[0][df],0,0,0);
        dq[1][df] = __builtin_amdgcn_mfma_f32_16x16x32_bf16(wf, xf[1][kc8], dq[1][df],0,0,0);
      }
    const float SCL = 0.125f * 1.44269504088896f;
    #pragma unroll
    for(int sub=0;sub<2;sub++)
      #pragma unroll
      for(int kc=0;kc<2;kc++){
        union{s16x8 v; u32 u[4];} t;
        t.u[0]=pkbf(dq[sub][2*kc][0]*SCL,  dq[sub][2*kc][1]*SCL);
        t.u[1]=pkbf(dq[sub][2*kc][2]*SCL,  dq[sub][2*kc][3]*SCL);
        t.u[2]=pkbf(dq[sub][2*kc+1][0]*SCL,dq[sub][2*kc+1][1]*SCL);
        t.u[3]=pkbf(dq[sub][2*kc+1][2]*SCL,dq[sub][2*kc+1][3]*SCL);
        qf[sub][kc]=t.v;
      }
  }

  // ---- ones A-fragment for l accumulation (permutation-immune) ----
  s16x8 ones;
  #pragma unroll
  for(int e=0;e<8;e++) ones[e] = (short)0x3F80;

  // ---- staging (row copies with write-side XOR swizzle) ----
  const int srow = tid>>2, sc = (tid&3)*16;
  const int xw = (srow&7)<<3;                     // write-side XOR
  const int c0w = sc ^ xw, c1w = (sc+8) ^ xw;
  const u16* kst = kg + (size_t)srow*64 + sc;
  const u16* vst = vg + (size_t)srow*2048 + sc;
  uint4 kr0,kr1,vr0,vr1;
  // stage tile 0 into buf 0
  kr0 = *(const uint4*)(kst);   kr1 = *(const uint4*)(kst+8);
  vr0 = *(const uint4*)(vst);   vr1 = *(const uint4*)(vst+8);
  *(uint4*)&kt[0][srow][c0w] = kr0;  *(uint4*)&kt[0][srow][c1w] = kr1;
  *(uint4*)&vt[0][srow][c0w] = vr0;  *(uint4*)&vt[0][srow][c1w] = vr1;
  // prefetch tile 1 into regs
  kr0 = *(const uint4*)(kst + 4096);  kr1 = *(const uint4*)(kst + 4096 + 8);
  vr0 = *(const uint4*)(vst + 64);    vr1 = *(const uint4*)(vst + 64 + 8);
  __syncthreads();

  const int xsw = (l16&7)<<3;                     // read-side XOR (matches rows' row&7)
  f32x4 oacc[2][4] = {};
  f32x4 accl[2] = {};

  for(int t=0;t<32;t++){
    const int cur = t&1, nb = cur^1;
    // ---- fragment reads of tile t from buf[cur] (XOR-swizzled columns) ----
    s16x8 kf[8], vf[8];
    #pragma unroll
    for(int jf=0;jf<4;jf++)
      #pragma unroll
      for(int kc=0;kc<2;kc++)
        kf[jf*2+kc] = *(const s16x8*)&kt[cur][jf*16+l16][(kc*32+lq*8) ^ xsw];
    #pragma unroll
    for(int cf=0;cf<4;cf++)
      #pragma unroll
      for(int kc=0;kc<2;kc++)
        vf[cf*2+kc] = *(const s16x8*)&vt[cur][cf*16+l16][(kc*32+lq*8) ^ xsw];

    // ---- write prefetched tile t+1 into buf[nb] (disjoint; prior barrier
    // guarantees all waves finished reading buf[nb] at t-1) ----
    if (t<31){
      *(uint4*)&kt[nb][srow][c0w] = kr0;  *(uint4*)&kt[nb][srow][c1w] = kr1;
      *(uint4*)&vt[nb][srow][c0w] = vr0;  *(uint4*)&vt[nb][srow][c1w] = vr1;
      if (t<30){                             // issue t+2 prefetch
        kr0 = *(const uint4*)(kst + (size_t)(t+2)*4096);
        kr1 = *(const uint4*)(kst + (size_t)(t+2)*4096 + 8);
        vr0 = *(const uint4*)(vst + (size_t)(t+2)*64);
        vr1 = *(const uint4*)(vst + (size_t)(t+2)*64 + 8);
      }
    }

    // ---- S^T = mfma(K, Q), kf shared across subtiles ----
    f32x4 sacc[2][4] = {};
    #pragma unroll
    for(int jf=0;jf<4;jf++)
      #pragma unroll
      for(int kc=0;kc<2;kc++){
        sacc[0][jf]=__builtin_amdgcn_mfma_f32_16x16x32_bf16(kf[jf*2+kc],qf[0][kc],sacc[0][jf],0,0,0);
        sacc[1][jf]=__builtin_amdgcn_mfma_f32_16x16x32_bf16(kf[jf*2+kc],qf[1][kc],sacc[1][jf],0,0,0);
      }
    // ---- softmax-lite: P = exp2(S) raw, pack to bf16 ----
    s16x8 pf[2][2];
    #pragma unroll
    for(int sub=0;sub<2;sub++)
      #pragma unroll
      for(int kc=0;kc<2;kc++){
        union{s16x8 v; u32 u[4];} tt;
        tt.u[0]=pkbf(exp2a(sacc[sub][2*kc][0]),  exp2a(sacc[sub][2*kc][1]));
        tt.u[1]=pkbf(exp2a(sacc[sub][2*kc][2]),  exp2a(sacc[sub][2*kc][3]));
        tt.u[2]=pkbf(exp2a(sacc[sub][2*kc+1][0]),exp2a(sacc[sub][2*kc+1][1]));
        tt.u[3]=pkbf(exp2a(sacc[sub][2*kc+1][2]),exp2a(sacc[sub][2*kc+1][3]));
        pf[sub][kc]=tt.v;
      }
    // ---- l += ones * P ----
    #pragma unroll
    for(int kc=0;kc<2;kc++){
      accl[0]=__builtin_amdgcn_mfma_f32_16x16x32_bf16(ones,pf[0][kc],accl[0],0,0,0);
      accl[1]=__builtin_amdgcn_mfma_f32_16x16x32_bf16(ones,pf[1][kc],accl[1],0,0,0);
    }
    // ---- O^T += mfma(V^T, P^T), vf shared across subtiles ----
    #pragma unroll
    for(int cf=0;cf<4;cf++)
      #pragma unroll
      for(int kc=0;kc<2;kc++){
        oacc[0][cf]=__builtin_amdgcn_mfma_f32_16x16x32_bf16(vf[cf*2+kc],pf[0][kc],oacc[0][cf],0,0,0);
        oacc[1][cf]=__builtin_amdgcn_mfma_f32_16x16x32_bf16(vf[cf*2+kc],pf[1][kc],oacc[1][cf],0,0,0);
      }
    if (t<31) __syncthreads();               // single barrier per tile
  }
  // ---- epilogue: rinv from accl (all rows identical), packed stores ----
  #pragma unroll
  for(int sub=0;sub<2;sub++){
    const float rinv = 1.f/accl[sub][0];
    const int n = n0 + w*32 + sub*16 + l16;
    #pragma unroll
    for(int cf=0;cf<4;cf++){
      uint2 st;
      st.x = pkbf(oacc[sub][cf][0]*rinv, oacc[sub][cf][1]*rinv);
      st.y = pkbf(oacc[sub][cf][2]*rinv, oacc[sub][cf][3]*rinv);
      *(uint2*)(catp + (size_t)n*512 + cf*16 + lq*4) = st;
    }
  }
}

// ---------------- Kernel 3: output projection + BN + LeakyReLU (fp32 out, Wp inline cvt) ----------------
__global__ __launch_bounds__(256) void proj_kernel(
    const u16* __restrict__ cat, const float* __restrict__ Wp32,
    const float* __restrict__ gamma, const float* __restrict__ beta,
    const float* __restrict__ mean,  const float* __restrict__ var,
    float* __restrict__ out)
{
  const int m0 = blockIdx.x*64, j0 = blockIdx.y*64;
  __shared__ u16 at[64][40];
  __shared__ u16 bt[64][40];
  const int tid=threadIdx.x, lane=tid&63, w=tid>>6;
  const int wm=w>>1, wn=w&1, l16=lane&15, lq=lane>>4;
  f32x4 acc[2][2]={};
  const int srow=tid>>2, scol=(tid&3)*8;
  for(int c0=0;c0<512;c0+=32){
    *(uint4*)&at[srow][scol] = *(const uint4*)&cat[(size_t)(m0+srow)*512 + c0+scol];
    {
      const float* wsrc = Wp32 + (size_t)(j0+srow)*512 + c0 + scol;
      float4 a = *(const float4*)wsrc;
      float4 b = *(const float4*)(wsrc+4);
      uint4 st; st.x=pkbf(a.x,a.y); st.y=pkbf(a.z,a.w); st.z=pkbf(b.x,b.y); st.w=pkbf(b.z,b.w);
      *(uint4*)&bt[srow][scol] = st;
    }
    __syncthreads();
    s16x8 af[2],bfr[2];
    #pragma unroll
    for(int mf=0;mf<2;mf++) af[mf]=ld_frag(&at[wm*32+mf*16+l16][lq*4]);
    #pragma unroll
    for(int nf=0;nf<2;nf++) bfr[nf]=ld_frag(&bt[wn*32+nf*16+l16][lq*4]);
    #pragma unroll
    for(int mf=0;mf<2;mf++)
      #pragma unroll
      for(int nf=0;nf<2;nf++)
        acc[mf][nf]=__builtin_amdgcn_mfma_f32_16x16x32_bf16(af[mf],bfr[nf],acc[mf][nf],0,0,0);
    __syncthreads();
  }
  #pragma unroll
  for(int nf=0;nf<2;nf++){
    const int co = j0 + wn*32 + nf*16 + l16;
    const float g=gamma[co], be=beta[co], mu=mean[co], va=var[co];
    const float a  = g * rsqrtf(va + 1e-5f);
    const float b2 = be - mu*a;
    #pragma unroll
    for(int mf=0;mf<2;mf++)
      #pragma unroll
      for(int r=0;r<4;r++){
        int m = m0 + wm*32 + mf*16 + lq*4 + r;
        float y = acc[mf][nf][r]*a + b2;
        y = (y>=0.f)? y : 0.01f*y;
        out[(size_t)m*256 + co] = y;
      }
  }
}

extern "C" void kernel_launch(void* const* d_in, const int* in_sizes, int n_in,
                              void* d_out, int out_size, void* d_ws, size_t ws_size,
                              hipStream_t stream)
{
  const float* x  = (const float*)d_in[0];
  const float* Wq = (const float*)d_in[1];
  const float* Wk = (const float*)d_in[2];
  const float* Wv = (const float*)d_in[3];
  const float* Wp = (const float*)d_in[4];
  const float* g  = (const float*)d_in[5];
  const float* be = (const float*)d_in[6];
  const float* mu = (const float*)d_in[7];
  const float* va = (const float*)d_in[8];

  u16* ws   = (u16*)d_ws;
  u16* wq16 = ws;                               // 131072 elems
  u16* kb   = ws + 131072;

  // full path: wq(0.25MiB) + kb(16MiB) + vb(16MiB) + cat(16MiB)
  const size_t full_elems = 131072ull + 8388608ull*3ull;   // 25,296,896 u16
  if (ws_size >= full_elems*2ull){
    u16* vb  = kb + 8388608;
    u16* cat = vb + 8388608;
    kv_kernel<<<dim3(256,8,2), dim3(256), 0, stream>>>(x, Wk, Wv, Wq, kb, vb, wq16);
    attn_kernel<<<dim3(1024), dim3(256), 0, stream>>>(x, wq16, kb, vb, cat, 8);
    proj_kernel<<<dim3(256,4), dim3(256), 0, stream>>>(cat, Wp, g, be, mu, va, (float*)d_out);
  } else {
    u16* vb  = kb + 4194304;
    u16* cat = vb + 4194304;
    for (int half = 0; half < 2; ++half){
      const float* xh = x + (size_t)half*2097152;   // 4 batches * 2048 * 256 f32
      u16* cath = cat + (size_t)half*4194304;
      kv_kernel<<<dim3(128,8,2), dim3(256), 0, stream>>>(xh, Wk, Wv, Wq, kb, vb, wq16);
      attn_kernel<<<dim3(512), dim3(256), 0, stream>>>(xh, wq16, kb, vb, cath, 4);
    }
    proj_kernel<<<dim3(256,4), dim3(256), 0, stream>>>(cat, Wp, g, be, mu, va, (float*)d_out);
  }
}

// Round 19
// 167.850 us; speedup vs baseline: 1.0297x; 1.0297x over previous
//
#include <hip/hip_runtime.h>
#include <hip/hip_bf16.h>

typedef unsigned short u16;
typedef unsigned int u32;
typedef float  f32x4 __attribute__((ext_vector_type(4)));
typedef short  s16x8 __attribute__((ext_vector_type(8)));

#define DEV static __device__ __forceinline__

DEV u16 f2bf(float f){ union{float f; unsigned int i;} c; c.f=f; unsigned int i=c.i;
                       return (u16)((i + 0x7FFFu + ((i>>16)&1u))>>16); }

// packed 2x f32 -> bf16x2 (v_cvt_pk_bf16_f32), low word = a
DEV u32 pkbf(float a, float b){
  union{ __hip_bfloat162 h; u32 u; } c;
  c.h = __float22bfloat162_rn(make_float2(a, b));
  return c.u;
}

DEV float exp2a(float x){
#if __has_builtin(__builtin_amdgcn_exp2f)
  return __builtin_amdgcn_exp2f(x);
#else
  return exp2f(x);
#endif
}

// 16x16x32 A/B fragment, plain bf16 layout: 4 contiguous bf16 at p, 4 at p+16.
// Same k-map mu(lq,e) for all operands (incl. D->B repacks) -> permutation-safe.
DEV s16x8 ld_frag(const u16* p){
  union{ s16x8 v; uint2 u[2]; } r;
  r.u[0] = *(const uint2*)(p);
  r.u[1] = *(const uint2*)(p+16);
  return r.v;
}

// Same fragment built from an fp32 source (inline convert; layout-identical).
DEV s16x8 ld_frag_f32(const float* p){
  float4 a = *(const float4*)(p);
  float4 b = *(const float4*)(p+16);
  union{ s16x8 v; u32 u[4]; } r;
  r.u[0]=pkbf(a.x,a.y); r.u[1]=pkbf(a.z,a.w);
  r.u[2]=pkbf(b.x,b.y); r.u[3]=pkbf(b.z,b.w);
  return r.v;
}

// ---------------- Kernel 1: K/V projection (x AND W read as fp32, converted inline) ----------------
// K stored [bh][n][kk'] (kk' fragment-permuted); V stored transposed
// [bh][dv][n'] (n' fragment-permuted within each 64-tile).
// Piggyback: 64 V-side blocks also convert Wq fp32->bf16 (no extra dispatch).
__global__ __launch_bounds__(256) void kv_kernel(
    const float* __restrict__ x32, const float* __restrict__ Wk32,
    const float* __restrict__ Wv32, const float* __restrict__ Wq32,
    u16* __restrict__ kbuf, u16* __restrict__ vbuf, u16* __restrict__ wq16)
{
  const int isV = blockIdx.z;
  const float* W32 = isV ? Wv32 : Wk32;
  const int m0 = blockIdx.x*64, j0 = blockIdx.y*64;
  __shared__ u16 at[64][40];
  __shared__ u16 bt[64][40];
  const int tid = threadIdx.x, lane = tid&63, w = tid>>6;
  const int wm = w>>1, wn = w&1;
  const int l16 = lane&15, lq = lane>>4;
  f32x4 acc[2][2] = {};
  const int srow = tid>>2, scol = (tid&3)*8;
  for (int c0=0;c0<256;c0+=32){
    {
      const float* xs = x32 + (size_t)(m0+srow)*256 + c0 + scol;
      float4 a = *(const float4*)xs;
      float4 b = *(const float4*)(xs+4);
      uint4 st; st.x=pkbf(a.x,a.y); st.y=pkbf(a.z,a.w); st.z=pkbf(b.x,b.y); st.w=pkbf(b.z,b.w);
      *(uint4*)&at[srow][scol] = st;
    }
    {
      const float* wsrc = W32 + (size_t)(j0+srow)*256 + c0 + scol;
      float4 a = *(const float4*)wsrc;
      float4 b = *(const float4*)(wsrc+4);
      uint4 st; st.x=pkbf(a.x,a.y); st.y=pkbf(a.z,a.w); st.z=pkbf(b.x,b.y); st.w=pkbf(b.z,b.w);
      *(uint4*)&bt[srow][scol] = st;
    }
    __syncthreads();
    s16x8 af[2], bfr[2];
    #pragma unroll
    for(int mf=0;mf<2;mf++) af[mf]  = ld_frag(&at[wm*32+mf*16+l16][lq*4]);
    #pragma unroll
    for(int nf=0;nf<2;nf++) bfr[nf] = ld_frag(&bt[wn*32+nf*16+l16][lq*4]);
    #pragma unroll
    for(int mf=0;mf<2;mf++)
      #pragma unroll
      for(int nf=0;nf<2;nf++)
        acc[mf][nf] = __builtin_amdgcn_mfma_f32_16x16x32_bf16(af[mf], bfr[nf], acc[mf][nf],0,0,0);
    __syncthreads();
  }
  // D layout: col = l16, row = lq*4 + r
  if (!isV){
    #pragma unroll
    for(int mf=0;mf<2;mf++)
      #pragma unroll
      for(int nf=0;nf<2;nf++){
        const int j  = j0 + wn*32 + nf*16 + l16;
        const int hh = j>>6;
        const int kkp = wn*32 + (l16>>2)*8 + nf*4 + (l16&3);   // permuted kk
        #pragma unroll
        for(int r=0;r<4;r++){
          int m = m0 + wm*32 + mf*16 + lq*4 + r;
          int blx = m>>11, n = m&2047;
          kbuf[(size_t)((blx<<3)|hh)*131072 + (size_t)n*64 + kkp] = f2bf(acc[mf][nf][r]);
        }
      }
  } else {
    const int blx = m0>>11;
    #pragma unroll
    for(int mf=0;mf<2;mf++){
      const int nn = (m0&2047) + wm*32 + lq*8 + mf*4;          // permuted n-within-tile
      #pragma unroll
      for(int nf=0;nf<2;nf++){
        const int j  = j0 + wn*32 + nf*16 + l16;
        const int hh = j>>6, kk = j&63;
        uint2 st;
        st.x = pkbf(acc[mf][nf][0], acc[mf][nf][1]);
        st.y = pkbf(acc[mf][nf][2], acc[mf][nf][3]);
        *(uint2*)&vbuf[(size_t)((blx<<3)|hh)*131072 + (size_t)kk*2048 + nn] = st;
      }
    }
    // ---- piggyback: Wq fp32 -> bf16 (64 blocks x 2048 elems) ----
    if (j0==0 && blockIdx.x < 64){
      const int base = blockIdx.x*2048 + tid*8;
      float4 a = *(const float4*)(Wq32 + base);
      float4 b = *(const float4*)(Wq32 + base + 4);
      uint4 st; st.x=pkbf(a.x,a.y); st.y=pkbf(a.z,a.w); st.z=pkbf(b.x,b.y); st.w=pkbf(b.z,b.w);
      *(uint4*)(wq16 + base) = st;
    }
  }
}

// ---------------- Kernel 2: fused Q-projection + flash attention ----------------
// EXACT round-16 structure (best attn: 132.9 us): 128 q-rows/block, XCD-swizzled
// grid, scale folded into Q, NO-max softmax (P=exp2(S) raw), l via ones-MFMA,
// SINGLE-buffered unpadded [64][64] LDS, 2 barriers/tile, both-sides XOR swizzle
// (0 bank conflicts), Wq read as bf16 (piggyback-converted).
__global__ __launch_bounds__(256) void attn_kernel(
    const float* __restrict__ x32, const u16* __restrict__ wq16,
    const u16* __restrict__ kb, const u16* __restrict__ vb,
    u16* __restrict__ cat, int bh_per_xcd)
{
  const int lin = blockIdx.x;
  const int xcd = lin & 7, slot = lin >> 3;
  const int bhl = xcd*bh_per_xcd + (slot>>4);     // 16 q-tiles per bh
  const int n0  = (slot & 15) * 128;
  const int bl = bhl>>3, h = bhl&7;
  const float* xg = x32 + (size_t)bl*524288;
  const u16* kg = kb + (size_t)bhl*131072;        // [n][kk'] pre-permuted
  const u16* vg = vb + (size_t)bhl*131072;        // [dv][n'] pre-permuted
  u16* catp = cat + (size_t)bl*1048576 + h*64;
  const int tid=threadIdx.x, lane=tid&63, w=tid>>6;
  const int l16=lane&15, lq=lane>>4;

  __shared__ __align__(16) u16 kt[64][64];
  __shared__ __align__(16) u16 vt[64][64];

  // ---- Q on the fly for 2 subtiles; scale (0.125*log2e) folded into qf ----
  s16x8 qf[2][2];
  {
    const u16* wqh = wq16 + (size_t)h*16384;
    s16x8 xf[2][8];
    #pragma unroll
    for(int sub=0;sub<2;sub++){
      const int row = n0 + w*32 + sub*16 + l16;
      #pragma unroll
      for(int kc8=0;kc8<8;kc8++)
        xf[sub][kc8] = ld_frag_f32(xg + (size_t)row*256 + kc8*32 + lq*4);
    }
    f32x4 dq[2][4] = {};
    #pragma unroll
    for(int df=0;df<4;df++)
      #pragma unroll
      for(int kc8=0;kc8<8;kc8++){
        s16x8 wf = ld_frag(wqh + (size_t)(df*16+l16)*256 + kc8*32 + lq*4);
        dq[0][df] = __builtin_amdgcn_mfma_f32_16x16x32_bf16(wf, xf[0][kc8], dq[0][df],0,0,0);
        dq[1][df] = __builtin_amdgcn_mfma_f32_16x16x32_bf16(wf, xf[1][kc8], dq[1][df],0,0,0);
      }
    const float SCL = 0.125f * 1.44269504088896f;
    #pragma unroll
    for(int sub=0;sub<2;sub++)
      #pragma unroll
      for(int kc=0;kc<2;kc++){
        union{s16x8 v; u32 u[4];} t;
        t.u[0]=pkbf(dq[sub][2*kc][0]*SCL,  dq[sub][2*kc][1]*SCL);
        t.u[1]=pkbf(dq[sub][2*kc][2]*SCL,  dq[sub][2*kc][3]*SCL);
        t.u[2]=pkbf(dq[sub][2*kc+1][0]*SCL,dq[sub][2*kc+1][1]*SCL);
        t.u[3]=pkbf(dq[sub][2*kc+1][2]*SCL,dq[sub][2*kc+1][3]*SCL);
        qf[sub][kc]=t.v;
      }
  }

  // ---- ones A-fragment for l accumulation (permutation-immune) ----
  s16x8 ones;
  #pragma unroll
  for(int e=0;e<8;e++) ones[e] = (short)0x3F80;

  // ---- staging (row copies with write-side XOR swizzle) ----
  const int srow = tid>>2, sc = (tid&3)*16;
  const int xw = (srow&7)<<3;                     // write-side XOR
  const int c0w = sc ^ xw, c1w = (sc+8) ^ xw;
  const u16* kst = kg + (size_t)srow*64 + sc;
  const u16* vst = vg + (size_t)srow*2048 + sc;
  uint4 kr0,kr1,vr0,vr1;
  // stage tile 0
  kr0 = *(const uint4*)(kst);   kr1 = *(const uint4*)(kst+8);
  vr0 = *(const uint4*)(vst);   vr1 = *(const uint4*)(vst+8);
  *(uint4*)&kt[srow][c0w] = kr0;  *(uint4*)&kt[srow][c1w] = kr1;
  *(uint4*)&vt[srow][c0w] = vr0;  *(uint4*)&vt[srow][c1w] = vr1;
  // prefetch tile 1 into regs
  kr0 = *(const uint4*)(kst + 4096);  kr1 = *(const uint4*)(kst + 4096 + 8);
  vr0 = *(const uint4*)(vst + 64);    vr1 = *(const uint4*)(vst + 64 + 8);
  __syncthreads();

  const int xsw = (l16&7)<<3;                     // read-side XOR (matches rows' row&7)
  f32x4 oacc[2][4] = {};
  f32x4 accl[2] = {};

  for(int t=0;t<32;t++){
    // ---- fragment reads of tile t (XOR-swizzled columns) ----
    s16x8 kf[8], vf[8];
    #pragma unroll
    for(int jf=0;jf<4;jf++)
      #pragma unroll
      for(int kc=0;kc<2;kc++)
        kf[jf*2+kc] = *(const s16x8*)&kt[jf*16+l16][(kc*32+lq*8) ^ xsw];
    #pragma unroll
    for(int cf=0;cf<4;cf++)
      #pragma unroll
      for(int kc=0;kc<2;kc++)
        vf[cf*2+kc] = *(const s16x8*)&vt[cf*16+l16][(kc*32+lq*8) ^ xsw];

    if (t<31){
      __syncthreads();                       // all waves done reading tile t
      *(uint4*)&kt[srow][c0w] = kr0;  *(uint4*)&kt[srow][c1w] = kr1;
      *(uint4*)&vt[srow][c0w] = vr0;  *(uint4*)&vt[srow][c1w] = vr1;
      if (t<30){                             // 2-deep prefetch
        kr0 = *(const uint4*)(kst + (size_t)(t+2)*4096);
        kr1 = *(const uint4*)(kst + (size_t)(t+2)*4096 + 8);
        vr0 = *(const uint4*)(vst + (size_t)(t+2)*64);
        vr1 = *(const uint4*)(vst + (size_t)(t+2)*64 + 8);
      }
    }

    // ---- S^T = mfma(K, Q), kf shared across subtiles ----
    f32x4 sacc[2][4] = {};
    #pragma unroll
    for(int jf=0;jf<4;jf++)
      #pragma unroll
      for(int kc=0;kc<2;kc++){
        sacc[0][jf]=__builtin_amdgcn_mfma_f32_16x16x32_bf16(kf[jf*2+kc],qf[0][kc],sacc[0][jf],0,0,0);
        sacc[1][jf]=__builtin_amdgcn_mfma_f32_16x16x32_bf16(kf[jf*2+kc],qf[1][kc],sacc[1][jf],0,0,0);
      }
    // ---- softmax-lite: P = exp2(S) raw, pack to bf16 ----
    s16x8 pf[2][2];
    #pragma unroll
    for(int sub=0;sub<2;sub++)
      #pragma unroll
      for(int kc=0;kc<2;kc++){
        union{s16x8 v; u32 u[4];} tt;
        tt.u[0]=pkbf(exp2a(sacc[sub][2*kc][0]),  exp2a(sacc[sub][2*kc][1]));
        tt.u[1]=pkbf(exp2a(sacc[sub][2*kc][2]),  exp2a(sacc[sub][2*kc][3]));
        tt.u[2]=pkbf(exp2a(sacc[sub][2*kc+1][0]),exp2a(sacc[sub][2*kc+1][1]));
        tt.u[3]=pkbf(exp2a(sacc[sub][2*kc+1][2]),exp2a(sacc[sub][2*kc+1][3]));
        pf[sub][kc]=tt.v;
      }
    // ---- l += ones * P ----
    #pragma unroll
    for(int kc=0;kc<2;kc++){
      accl[0]=__builtin_amdgcn_mfma_f32_16x16x32_bf16(ones,pf[0][kc],accl[0],0,0,0);
      accl[1]=__builtin_amdgcn_mfma_f32_16x16x32_bf16(ones,pf[1][kc],accl[1],0,0,0);
    }
    // ---- O^T += mfma(V^T, P^T), vf shared across subtiles ----
    #pragma unroll
    for(int cf=0;cf<4;cf++)
      #pragma unroll
      for(int kc=0;kc<2;kc++){
        oacc[0][cf]=__builtin_amdgcn_mfma_f32_16x16x32_bf16(vf[cf*2+kc],pf[0][kc],oacc[0][cf],0,0,0);
        oacc[1][cf]=__builtin_amdgcn_mfma_f32_16x16x32_bf16(vf[cf*2+kc],pf[1][kc],oacc[1][cf],0,0,0);
      }
    if (t<31) __syncthreads();               // writes of tile t+1 visible
  }
  // ---- epilogue: rinv from accl (all rows identical), packed stores ----
  #pragma unroll
  for(int sub=0;sub<2;sub++){
    const float rinv = 1.f/accl[sub][0];
    const int n = n0 + w*32 + sub*16 + l16;
    #pragma unroll
    for(int cf=0;cf<4;cf++){
      uint2 st;
      st.x = pkbf(oacc[sub][cf][0]*rinv, oacc[sub][cf][1]*rinv);
      st.y = pkbf(oacc[sub][cf][2]*rinv, oacc[sub][cf][3]*rinv);
      *(uint2*)(catp + (size_t)n*512 + cf*16 + lq*4) = st;
    }
  }
}

// ---------------- Kernel 3: output projection + BN + LeakyReLU (fp32 out, Wp inline cvt) ----------------
__global__ __launch_bounds__(256) void proj_kernel(
    const u16* __restrict__ cat, const float* __restrict__ Wp32,
    const float* __restrict__ gamma, const float* __restrict__ beta,
    const float* __restrict__ mean,  const float* __restrict__ var,
    float* __restrict__ out)
{
  const int m0 = blockIdx.x*64, j0 = blockIdx.y*64;
  __shared__ u16 at[64][40];
  __shared__ u16 bt[64][40];
  const int tid=threadIdx.x, lane=tid&63, w=tid>>6;
  const int wm=w>>1, wn=w&1, l16=lane&15, lq=lane>>4;
  f32x4 acc[2][2]={};
  const int srow=tid>>2, scol=(tid&3)*8;
  for(int c0=0;c0<512;c0+=32){
    *(uint4*)&at[srow][scol] = *(const uint4*)&cat[(size_t)(m0+srow)*512 + c0+scol];
    {
      const float* wsrc = Wp32 + (size_t)(j0+srow)*512 + c0 + scol;
      float4 a = *(const float4*)wsrc;
      float4 b = *(const float4*)(wsrc+4);
      uint4 st; st.x=pkbf(a.x,a.y); st.y=pkbf(a.z,a.w); st.z=pkbf(b.x,b.y); st.w=pkbf(b.z,b.w);
      *(uint4*)&bt[srow][scol] = st;
    }
    __syncthreads();
    s16x8 af[2],bfr[2];
    #pragma unroll
    for(int mf=0;mf<2;mf++) af[mf]=ld_frag(&at[wm*32+mf*16+l16][lq*4]);
    #pragma unroll
    for(int nf=0;nf<2;nf++) bfr[nf]=ld_frag(&bt[wn*32+nf*16+l16][lq*4]);
    #pragma unroll
    for(int mf=0;mf<2;mf++)
      #pragma unroll
      for(int nf=0;nf<2;nf++)
        acc[mf][nf]=__builtin_amdgcn_mfma_f32_16x16x32_bf16(af[mf],bfr[nf],acc[mf][nf],0,0,0);
    __syncthreads();
  }
  #pragma unroll
  for(int nf=0;nf<2;nf++){
    const int co = j0 + wn*32 + nf*16 + l16;
    const float g=gamma[co], be=beta[co], mu=mean[co], va=var[co];
    const float a  = g * rsqrtf(va + 1e-5f);
    const float b2 = be - mu*a;
    #pragma unroll
    for(int mf=0;mf<2;mf++)
      #pragma unroll
      for(int r=0;r<4;r++){
        int m = m0 + wm*32 + mf*16 + lq*4 + r;
        float y = acc[mf][nf][r]*a + b2;
        y = (y>=0.f)? y : 0.01f*y;
        out[(size_t)m*256 + co] = y;
      }
  }
}

extern "C" void kernel_launch(void* const* d_in, const int* in_sizes, int n_in,
                              void* d_out, int out_size, void* d_ws, size_t ws_size,
                              hipStream_t stream)
{
  const float* x  = (const float*)d_in[0];
  const float* Wq = (const float*)d_in[1];
  const float* Wk = (const float*)d_in[2];
  const float* Wv = (const float*)d_in[3];
  const float* Wp = (const float*)d_in[4];
  const float* g  = (const float*)d_in[5];
  const float* be = (const float*)d_in[6];
  const float* mu = (const float*)d_in[7];
  const float* va = (const float*)d_in[8];

  u16* ws   = (u16*)d_ws;
  u16* wq16 = ws;                               // 131072 elems
  u16* kb   = ws + 131072;

  // full path: wq(0.25MiB) + kb(16MiB) + vb(16MiB) + cat(16MiB)
  const size_t full_elems = 131072ull + 8388608ull*3ull;   // 25,296,896 u16
  if (ws_size >= full_elems*2ull){
    u16* vb  = kb + 8388608;
    u16* cat = vb + 8388608;
    kv_kernel<<<dim3(256,8,2), dim3(256), 0, stream>>>(x, Wk, Wv, Wq, kb, vb, wq16);
    attn_kernel<<<dim3(1024), dim3(256), 0, stream>>>(x, wq16, kb, vb, cat, 8);
    proj_kernel<<<dim3(256,4), dim3(256), 0, stream>>>(cat, Wp, g, be, mu, va, (float*)d_out);
  } else {
    u16* vb  = kb + 4194304;
    u16* cat = vb + 4194304;
    for (int half = 0; half < 2; ++half){
      const float* xh = x + (size_t)half*2097152;   // 4 batches * 2048 * 256 f32
      u16* cath = cat + (size_t)half*4194304;
      kv_kernel<<<dim3(128,8,2), dim3(256), 0, stream>>>(xh, Wk, Wv, Wq, kb, vb, wq16);
      attn_kernel<<<dim3(512), dim3(256), 0, stream>>>(xh, wq16, kb, vb, cath, 4);
    }
    proj_kernel<<<dim3(256,4), dim3(256), 0, stream>>>(cat, Wp, g, be, mu, va, (float*)d_out);
  }
}